// Round 9
// baseline (300.005 us; speedup 1.0000x reference)
//
#include <hip/hip_runtime.h>

// GCNConv(100k nodes, 1M edges, D=128) + two heads (128->64), fp32.
// R9: k_final LDS bank-conflict fix: strided column mapping (c = j4*32+cg*4)
// makes Ws reads conflict-free (was 4-way on all 512 reads/thread); Xs row
// stride padded to 132 floats -> conflict-free Xs reads. Rest unchanged.
//
// ws: hist_g[NB*512] | bucketTotal[NB] | bucketStart[NB+1] | ebuf[E] int2
//     | off[n+1] | dinv[n] | csr[E] | aggx[n*128] f32 | Wf | bf | xh bf16

#define BLOCK 256
#define BM 128
#define BK 32
#define XP 132          // padded Xs row stride (floats), 16B-aligned
#define SB 512          // scatter blocks (pass A/C)
#define NB_MAX 784      // max coarse buckets (n<=100352)
#define CONV_BLOCKS 4096

__device__ inline unsigned short f2bf(float f) {
    unsigned u = __float_as_uint(f);
    unsigned r = (u + 0x7FFF + ((u >> 16) & 1)) >> 16;  // RNE
    return (unsigned short)r;
}
__device__ inline float bf2f(unsigned short u) {
    return __uint_as_float(((unsigned)u) << 16);
}

// ---------------- prep: weight fusion | x->bf16 | pass A (bucket count) ----------------

__global__ __launch_bounds__(BLOCK) void k_prep(const float* __restrict__ x,
                                                const int* __restrict__ dst, int E,
                                                const float* __restrict__ Wg,
                                                const float* __restrict__ Wh,
                                                const float* __restrict__ Wl,
                                                const float* __restrict__ bg,
                                                const float* __restrict__ bh,
                                                const float* __restrict__ bl,
                                                float* __restrict__ Wf,
                                                float* __restrict__ bf,
                                                int* __restrict__ hist_g,
                                                unsigned short* __restrict__ xh,
                                                int n, int NB) {
    __shared__ int hist[NB_MAX];
    int b = blockIdx.x;
    if (b < 16) {  // Wf = Wg @ [Wh|Wl]
        int r = b * 8 + (threadIdx.x >> 5);
        int c0 = (threadIdx.x & 31) * 4;
        float a0 = 0.f, a1 = 0.f, a2 = 0.f, a3 = 0.f;
        for (int j = 0; j < 128; j++) {
            float wg = Wg[r * 128 + j];
            float4 wc;
            if (c0 < 64) wc = *(const float4*)(Wh + j * 64 + c0);
            else         wc = *(const float4*)(Wl + j * 64 + (c0 - 64));
            a0 += wg * wc.x; a1 += wg * wc.y; a2 += wg * wc.z; a3 += wg * wc.w;
        }
        *(float4*)(Wf + r * 128 + c0) = make_float4(a0, a1, a2, a3);
    } else if (b == 16) {  // bf = bg @ [Wh|Wl] + [bh|bl]
        int c = threadIdx.x;
        if (c < 128) {
            float acc = (c < 64) ? bh[c] : bl[c - 64];
            for (int j = 0; j < 128; j++) {
                float wc = (c < 64) ? Wh[j * 64 + c] : Wl[j * 64 + (c - 64)];
                acc += bg[j] * wc;
            }
            bf[c] = acc;
        }
    } else if (b < 17 + SB) {  // pass A: LDS bucket histogram of this block's chunk
        int blk = b - 17;
        for (int i = threadIdx.x; i < NB; i += BLOCK) hist[i] = 0;
        __syncthreads();
        int chunk = (E + SB - 1) / SB;
        int e0 = blk * chunk, e1 = min(E, e0 + chunk);
        for (int e = e0 + threadIdx.x; e < e1; e += BLOCK)
            atomicAdd(&hist[dst[e] >> 7], 1);
        __syncthreads();
        for (int i = threadIdx.x; i < NB; i += BLOCK)
            hist_g[(size_t)i * SB + blk] = hist[i];
    } else {  // x -> bf16
        const float4* x4 = (const float4*)x;
        ushort4* o4 = (ushort4*)xh;
        int total = n * 32;
        int i = (b - 17 - SB) * BLOCK + threadIdx.x;
        int stride = CONV_BLOCKS * BLOCK;
        for (; i < total; i += stride) {
            float4 v = x4[i];
            ushort4 o;
            o.x = f2bf(v.x); o.y = f2bf(v.y); o.z = f2bf(v.z); o.w = f2bf(v.w);
            o4[i] = o;
        }
    }
}

// ---------------- scan A: per-bucket exclusive prefix over SB blocks ----------------

__global__ __launch_bounds__(BLOCK) void k_scanA(int* __restrict__ hist_g,
                                                 int* __restrict__ bucketTotal, int NB) {
    __shared__ int s[SB];
    int bkt = blockIdx.x;
    int t = threadIdx.x;
    int a0 = hist_g[(size_t)bkt * SB + t];
    int a1 = hist_g[(size_t)bkt * SB + t + 256];
    s[t] = a0; s[t + 256] = a1;
    __syncthreads();
    for (int ofs = 1; ofs < SB; ofs <<= 1) {
        int v0 = (t >= ofs) ? s[t - ofs] : 0;
        int v1 = (t + 256 >= ofs) ? s[t + 256 - ofs] : 0;
        __syncthreads();
        s[t] += v0; s[t + 256] += v1;
        __syncthreads();
    }
    hist_g[(size_t)bkt * SB + t] = s[t] - a0;              // exclusive
    hist_g[(size_t)bkt * SB + t + 256] = s[t + 256] - a1;
    if (t == 255) bucketTotal[bkt] = s[SB - 1];
}

// ---------------- scan B: exclusive scan over buckets ----------------

__global__ __launch_bounds__(1024) void k_scanB(const int* __restrict__ bucketTotal,
                                                int* __restrict__ bucketStart,
                                                int NB, int E) {
    __shared__ int s[1024];
    int t = threadIdx.x;
    int v = (t < NB) ? bucketTotal[t] : 0;
    s[t] = v;
    __syncthreads();
    for (int ofs = 1; ofs < 1024; ofs <<= 1) {
        int u = (t >= ofs) ? s[t - ofs] : 0;
        __syncthreads();
        s[t] += u;
        __syncthreads();
    }
    if (t < NB) bucketStart[t] = s[t] - v;
    if (t == NB - 1) bucketStart[NB] = E;
}

// ---------------- pass C: scatter edges into bucket-grouped ebuf ----------------

__global__ __launch_bounds__(BLOCK) void k_scatter(const int* __restrict__ src,
                                                   const int* __restrict__ dst, int E,
                                                   const int* __restrict__ hist_g,
                                                   const int* __restrict__ bucketStart,
                                                   int2* __restrict__ ebuf, int NB) {
    __shared__ int cur[NB_MAX];
    int blk = blockIdx.x;
    for (int i = threadIdx.x; i < NB; i += BLOCK)
        cur[i] = bucketStart[i] + hist_g[(size_t)i * SB + blk];
    __syncthreads();
    int chunk = (E + SB - 1) / SB;
    int e0 = blk * chunk, e1 = min(E, e0 + chunk);
    for (int e = e0 + threadIdx.x; e < e1; e += BLOCK) {
        int d = dst[e];
        int pos = atomicAdd(&cur[d >> 7], 1);  // LDS atomic
        ebuf[pos] = make_int2(d, src[e]);
    }
}

// ---------------- pass D: per-bucket fine sort -> compact CSR + dinv ----------------

__global__ __launch_bounds__(BLOCK) void k_node(const int2* __restrict__ ebuf,
                                                const int* __restrict__ bucketStart,
                                                int* __restrict__ off,
                                                float* __restrict__ dinv,
                                                int* __restrict__ csr,
                                                int n, int NB, int E) {
    __shared__ int cnt[128];
    __shared__ int pre[128];
    __shared__ int cur[128];
    int bkt = blockIdx.x;
    int t = threadIdx.x;
    int node0 = bkt << 7;
    int nn = min(128, n - node0);
    int eb0 = bucketStart[bkt], eb1 = bucketStart[bkt + 1];

    if (t < 128) cnt[t] = 0;
    __syncthreads();
    for (int e = eb0 + t; e < eb1; e += BLOCK)
        atomicAdd(&cnt[ebuf[e].x & 127], 1);
    __syncthreads();
    if (t < 128) pre[t] = cnt[t];
    __syncthreads();
    for (int ofs = 1; ofs < 128; ofs <<= 1) {
        int v = (t < 128 && t >= ofs) ? pre[t - ofs] : 0;
        __syncthreads();
        if (t < 128) pre[t] += v;
        __syncthreads();
    }
    if (t < 128) cur[t] = pre[t] - cnt[t];
    __syncthreads();
    if (t < nn) {
        off[node0 + t] = eb0 + cur[t];
        dinv[node0 + t] = rsqrtf((float)(cnt[t] + 1));
    }
    if (bkt == 0 && t == 0) off[n] = E;
    for (int e = eb0 + t; e < eb1; e += BLOCK) {
        int2 p = ebuf[e];
        int pos = atomicAdd(&cur[p.x & 127], 1);  // LDS atomic
        csr[eb0 + pos] = p.y;
    }
}

// ---------------- gather: aggx[d] = dv*sum(dinv[s]*x[s]) + dv^2*x[d] ----------------

__global__ __launch_bounds__(BLOCK) void k_gather(const int* __restrict__ off,
                                                  const int* __restrict__ csr,
                                                  const float* __restrict__ dinv,
                                                  const unsigned short* __restrict__ xh,
                                                  const float* __restrict__ x,
                                                  float* __restrict__ aggx, int n) {
    int wave = (blockIdx.x * blockDim.x + threadIdx.x) >> 6;
    int lane = threadIdx.x & 63;
    if (wave >= n) return;
    int d = wave;
    int beg = off[d], end = off[d + 1];

    float accx = 0.f, accy = 0.f;
    for (int base = beg; base < end; base += 64) {
        int cnt = min(64, end - base);
        int s = 0; float w = 0.f;
        if (lane < cnt) { s = csr[base + lane]; w = dinv[s]; }
        int j = 0;
        for (; j + 4 <= cnt; j += 4) {
            int s0 = __shfl(s, j);
            int s1 = __shfl(s, j + 1);
            int s2 = __shfl(s, j + 2);
            int s3 = __shfl(s, j + 3);
            float w0 = __shfl(w, j);
            float w1 = __shfl(w, j + 1);
            float w2 = __shfl(w, j + 2);
            float w3 = __shfl(w, j + 3);
            ushort2 v0 = ((const ushort2*)(xh + (size_t)s0 * 128))[lane];
            ushort2 v1 = ((const ushort2*)(xh + (size_t)s1 * 128))[lane];
            ushort2 v2 = ((const ushort2*)(xh + (size_t)s2 * 128))[lane];
            ushort2 v3 = ((const ushort2*)(xh + (size_t)s3 * 128))[lane];
            accx += w0 * bf2f(v0.x) + w1 * bf2f(v1.x) + w2 * bf2f(v2.x) + w3 * bf2f(v3.x);
            accy += w0 * bf2f(v0.y) + w1 * bf2f(v1.y) + w2 * bf2f(v2.y) + w3 * bf2f(v3.y);
        }
        for (; j < cnt; j++) {
            int sj = __shfl(s, j);
            float wj = __shfl(w, j);
            ushort2 v = ((const ushort2*)(xh + (size_t)sj * 128))[lane];
            accx += wj * bf2f(v.x);
            accy += wj * bf2f(v.y);
        }
    }
    float dv = dinv[d];
    float2 xv = ((const float2*)(x + (size_t)d * 128))[lane];  // self-loop fp32
    float2 o;
    o.x = dv * accx + dv * dv * xv.x;
    o.y = dv * accy + dv * dv * xv.y;
    ((float2*)(aggx + (size_t)d * 128))[lane] = o;
}

// ---------------- tiled GEMM: out = aggx @ Wf + bf ----------------
// thread tile 4 rows x 16 cols, cols STRIDED: c = j4*32 + cg*4 + jj.
// Ws reads: 8 cg-addresses at 16B stride -> all 32 banks once, conflict-free.
// Xs rows padded to 132 floats -> conflict-free b128 reads.

__global__ __launch_bounds__(BLOCK) void k_final(const float* __restrict__ aggx,
                                                 const float* __restrict__ Wf,
                                                 const float* __restrict__ bf,
                                                 float* __restrict__ out, int n) {
    __shared__ float Xs[BK][XP];
    __shared__ float Ws[BK][BM];
    int rg = threadIdx.x >> 3;
    int cg = threadIdx.x & 7;
    int row0 = blockIdx.x * BM;

    float acc[4][16];
#pragma unroll
    for (int r = 0; r < 4; r++)
#pragma unroll
        for (int j = 0; j < 16; j++) acc[r][j] = 0.f;

    for (int kt = 0; kt < 128; kt += BK) {
        int kt4 = kt >> 2;
#pragma unroll
        for (int i = 0; i < 4; i++) {
            int s = threadIdx.x + i * 256;
            int r = s >> 3;
            int c4 = s & 7;
            int gr = row0 + r;
            if (gr >= n) gr = n - 1;
            float4 v = ((const float4*)(aggx + (size_t)gr * 128))[kt4 + c4];
            Xs[c4 * 4 + 0][r] = v.x;
            Xs[c4 * 4 + 1][r] = v.y;
            Xs[c4 * 4 + 2][r] = v.z;
            Xs[c4 * 4 + 3][r] = v.w;
        }
#pragma unroll
        for (int i = 0; i < 4; i++) {
            int s = threadIdx.x + i * 256;
            int k = s >> 5;
            int c4 = s & 31;
            float4 v = ((const float4*)(Wf + (size_t)(kt + k) * 128))[c4];
            *(float4*)&Ws[k][c4 * 4] = v;
        }
        __syncthreads();

#pragma unroll 4
        for (int k = 0; k < BK; k++) {
            float xf[4];
            *(float4*)xf = *(const float4*)&Xs[k][rg * 4];
            float wf[16];
#pragma unroll
            for (int j4 = 0; j4 < 4; j4++)
                *(float4*)&wf[j4 * 4] = *(const float4*)&Ws[k][j4 * 32 + cg * 4];
#pragma unroll
            for (int r = 0; r < 4; r++)
#pragma unroll
                for (int j = 0; j < 16; j++) acc[r][j] += xf[r] * wf[j];
        }
        __syncthreads();
    }

    // bias per strided column group
    float bvf[16];
#pragma unroll
    for (int j4 = 0; j4 < 4; j4++)
        *(float4*)&bvf[j4 * 4] = *(const float4*)(bf + j4 * 32 + cg * 4);

    float* high = out;
    float* low = out + (size_t)n * 64;
#pragma unroll
    for (int r = 0; r < 4; r++) {
        int row = row0 + rg * 4 + r;
        if (row >= n) break;
#pragma unroll
        for (int j4 = 0; j4 < 4; j4++) {
            int c = j4 * 32 + cg * 4;  // global fused column
            float4 v = make_float4(acc[r][j4 * 4 + 0] + bvf[j4 * 4 + 0],
                                   acc[r][j4 * 4 + 1] + bvf[j4 * 4 + 1],
                                   acc[r][j4 * 4 + 2] + bvf[j4 * 4 + 2],
                                   acc[r][j4 * 4 + 3] + bvf[j4 * 4 + 3]);
            if (c < 64)
                *(float4*)(high + (size_t)row * 64 + c) = v;
            else
                *(float4*)(low + (size_t)row * 64 + (c - 64)) = v;
        }
    }
}

extern "C" void kernel_launch(void* const* d_in, const int* in_sizes, int n_in,
                              void* d_out, int out_size, void* d_ws, size_t ws_size,
                              hipStream_t stream) {
    const float* x  = (const float*)d_in[0];
    const int*   ei = (const int*)d_in[1];
    const float* Wg = (const float*)d_in[2];
    const float* bg = (const float*)d_in[3];
    const float* Wh = (const float*)d_in[4];
    const float* bh = (const float*)d_in[5];
    const float* Wl = (const float*)d_in[6];
    const float* bl = (const float*)d_in[7];
    float* out = (float*)d_out;

    int n = in_sizes[0] / 128;
    int E = in_sizes[1] / 2;
    const int* src = ei;
    const int* dst = ei + E;
    int NB = (n + 127) >> 7;

    char* ws = (char*)d_ws;
    int*   hist_g      = (int*)ws;                ws += (size_t)NB_MAX * SB * 4;
    int*   bucketTotal = (int*)ws;                ws += (size_t)NB_MAX * 4;
    int*   bucketStart = (int*)ws;                ws += (size_t)(NB_MAX + 1) * 4;
    int2*  ebuf        = (int2*)ws;               ws += (size_t)E * 8;
    int*   off         = (int*)ws;                ws += (size_t)(n + 1) * 4;
    float* dinv        = (float*)ws;              ws += (size_t)n * 4;
    int*   csr         = (int*)ws;                ws += (size_t)E * 4;
    float* aggx        = (float*)ws;              ws += (size_t)n * 128 * 4;
    float* Wf          = (float*)ws;              ws += (size_t)128 * 128 * 4;
    float* bf          = (float*)ws;              ws += (size_t)128 * 4;
    unsigned short* xh = (unsigned short*)ws;

    k_prep<<<17 + SB + CONV_BLOCKS, BLOCK, 0, stream>>>(
        x, dst, E, Wg, Wh, Wl, bg, bh, bl, Wf, bf, hist_g, xh, n, NB);
    k_scanA<<<NB, BLOCK, 0, stream>>>(hist_g, bucketTotal, NB);
    k_scanB<<<1, 1024, 0, stream>>>(bucketTotal, bucketStart, NB, E);
    k_scatter<<<SB, BLOCK, 0, stream>>>(src, dst, E, hist_g, bucketStart, ebuf, NB);
    k_node<<<NB, BLOCK, 0, stream>>>(ebuf, bucketStart, off, dinv, csr, n, NB, E);
    k_gather<<<((size_t)n * 64 + BLOCK - 1) / BLOCK, BLOCK, 0, stream>>>(
        off, csr, dinv, xh, x, aggx, n);
    k_final<<<(n + BM - 1) / BM, BLOCK, 0, stream>>>(aggx, Wf, bf, out, n);
}